// Round 10
// baseline (347.683 us; speedup 1.0000x reference)
//
#include <hip/hip_runtime.h>

#pragma clang fp contract(off)

#define NB 8
#define KSEL 6000
#define KPAD 6016
#define PROP 1000
#define EQCAP 8192
#define NTILE 94
#define RMAX 2048
#define RTILES 32
#define SWORDS 32

// ws layout (bytes)
#define OFF_HIST1 0u          // 8*4096*4 = 131072
#define OFF_HIST2 131072u     // 8*4096*4
#define OFF_HIST3 262144u     // 8*256*4 = 8192
#define OFF_CTRL  270336u     // 8*64 = 512
#define OFF_SEL   270848u     // 8*6016*8 = 385024
#define OFF_EQ    655872u     // 8*8192*4 = 262144
#define OFF_BOX   1110528u    // 8*6016*16 = 770048 -> end 1880576
#define OFF_MAT   1884160u    // 8*32*2048*8 = 4194304 -> end 6078464
#define MAT_BYTES 4194304ull

struct Ctrl {
  unsigned t1, rem1, t2, rem2, thr, needEq, selCount, eqCount, total;
  unsigned pad[7];
};

__global__ __launch_bounds__(256) void zero_kernel(unsigned* p, int n) {
  int i = blockIdx.x * 256 + threadIdx.x;
  if (i < n) p[i] = 0u;
}

// phase 1: bin = bits>>20 (4096 bins); phase 2: mid 12 bits within t1; phase 3: low 8 bits within (t1,t2)
__global__ __launch_bounds__(256) void hist_kernel(int phase, const float* __restrict__ probs,
                                                   unsigned* __restrict__ hist,
                                                   const Ctrl* __restrict__ ctrl, int N) {
  __shared__ unsigned lh[4096];
  const int b = blockIdx.y;
  const int nb = (phase == 3) ? 256 : 4096;
  for (int k = threadIdx.x; k < nb; k += 256) lh[k] = 0u;
  unsigned t1 = 0, pre24 = 0;
  if (phase == 2) t1 = ctrl[b].t1;
  if (phase == 3) pre24 = (ctrl[b].t1 << 12) | ctrl[b].t2;
  __syncthreads();
  const int start = blockIdx.x * 4096;
  const int end = min(start + 4096, N);
  for (int i = start + (int)threadIdx.x * 2; i < end; i += 512) {
    const float4 p2 = *(const float4*)(probs + ((size_t)b * N + i) * 2);
    const unsigned bits0 = __float_as_uint(p2.y);
    if (phase == 1) atomicAdd(&lh[bits0 >> 20], 1u);
    else if (phase == 2) { if ((bits0 >> 20) == t1) atomicAdd(&lh[(bits0 >> 8) & 0xFFFu], 1u); }
    else { if ((bits0 >> 8) == pre24) atomicAdd(&lh[bits0 & 0xFFu], 1u); }
    if (i + 1 < end) {
      const unsigned bits1 = __float_as_uint(p2.w);
      if (phase == 1) atomicAdd(&lh[bits1 >> 20], 1u);
      else if (phase == 2) { if ((bits1 >> 20) == t1) atomicAdd(&lh[(bits1 >> 8) & 0xFFFu], 1u); }
      else { if ((bits1 >> 8) == pre24) atomicAdd(&lh[bits1 & 0xFFu], 1u); }
    }
  }
  __syncthreads();
  for (int k = threadIdx.x; k < nb; k += 256) {
    const unsigned v = lh[k];
    if (v) atomicAdd(&hist[b * nb + k], v);
  }
}

// one wave per image: descending cumulative scan, find threshold bin
__global__ __launch_bounds__(64) void scan_kernel(int phase, const unsigned* __restrict__ hist,
                                                  Ctrl* __restrict__ ctrl) {
  const int b = blockIdx.x;
  const int lane = threadIdx.x;
  const int nb = (phase == 3) ? 256 : 4096;
  const int chunks = nb >> 6;
  const unsigned target = (phase == 1) ? 6000u : ((phase == 2) ? ctrl[b].rem1 : ctrl[b].rem2);
  const unsigned* h = hist + b * nb;
  const int topbin = nb - 1 - lane * chunks;
  unsigned mysum = 0;
  for (int c = 0; c < chunks; c++) mysum += h[topbin - c];
  unsigned cum = mysum;
  for (int off = 1; off < 64; off <<= 1) {
    const unsigned v = __shfl_up(cum, off, 64);
    if (lane >= off) cum += v;
  }
  const unsigned prev = cum - mysum;
  if (prev < target && cum >= target) {
    unsigned c2 = prev;
    for (int c = 0; c < chunks; c++) {
      const int bin = topbin - c;
      const unsigned hv = h[bin];
      if (c2 + hv >= target) {
        const unsigned rem = target - c2;
        if (phase == 1) { ctrl[b].t1 = (unsigned)bin; ctrl[b].rem1 = rem; }
        else if (phase == 2) { ctrl[b].t2 = (unsigned)bin; ctrl[b].rem2 = rem; }
        else {
          ctrl[b].thr = (ctrl[b].t1 << 20) | (ctrl[b].t2 << 8) | (unsigned)bin;
          ctrl[b].needEq = rem;
        }
        break;
      }
      c2 += hv;
    }
  }
}

__global__ __launch_bounds__(256) void compact_kernel(const float* __restrict__ probs, Ctrl* __restrict__ ctrl,
                                                      unsigned long long* __restrict__ sel,
                                                      unsigned* __restrict__ eqBuf, int N) {
  const int b = blockIdx.y;
  const unsigned THR = ctrl[b].thr;
  const int start = blockIdx.x * 4096;
  const int end = min(start + 4096, N);
  const int lane = threadIdx.x & 63;
  const int iters = (end - start + 255) / 256;
  for (int it = 0; it < iters; it++) {
    const int i = start + it * 256 + (int)threadIdx.x;
    const bool v = i < end;
    unsigned bits = 0u;
    if (v) bits = __float_as_uint(probs[(size_t)(b * N + i) * 2 + 1]);
    const bool gt = v && (bits > THR);
    const bool eq = v && (bits == THR);
    const unsigned long long mg = __ballot(gt);
    if (mg) {
      const int leader = __builtin_ctzll(mg);
      unsigned base = 0;
      if (lane == leader) base = atomicAdd(&ctrl[b].selCount, (unsigned)__builtin_popcountll(mg));
      base = (unsigned)__shfl((int)base, leader, 64);
      if (gt) {
        const int rank = __builtin_popcountll(mg & ((1ull << lane) - 1ull));
        const unsigned pos = base + (unsigned)rank;
        if (pos < (unsigned)KPAD) sel[b * KPAD + pos] = ((unsigned long long)bits << 32) | (unsigned)i;
      }
    }
    const unsigned long long me = __ballot(eq);
    if (me) {
      const int leader = __builtin_ctzll(me);
      unsigned base = 0;
      if (lane == leader) base = atomicAdd(&ctrl[b].eqCount, (unsigned)__builtin_popcountll(me));
      base = (unsigned)__shfl((int)base, leader, 64);
      if (eq) {
        const int rank = __builtin_popcountll(me & ((1ull << lane) - 1ull));
        const unsigned pos = base + (unsigned)rank;
        if (pos < (unsigned)EQCAP) eqBuf[b * EQCAP + pos] = (unsigned)i;
      }
    }
  }
}

// resolve ties at the exact threshold: take lowest indices
__global__ __launch_bounds__(256) void eqres_kernel(Ctrl* __restrict__ ctrl, const unsigned* __restrict__ eqBuf,
                                                    unsigned long long* __restrict__ sel) {
  __shared__ unsigned si[EQCAP];
  const int b = blockIdx.x;
  const unsigned need = ctrl[b].needEq;
  unsigned cnt = ctrl[b].eqCount; if (cnt > EQCAP) cnt = EQCAP;
  const unsigned base = ctrl[b].selCount;
  const unsigned long long thrHi = ((unsigned long long)ctrl[b].thr) << 32;
  if (cnt <= need) {
    for (unsigned e = threadIdx.x; e < cnt; e += 256)
      sel[b * KPAD + base + e] = thrHi | (unsigned long long)eqBuf[b * EQCAP + e];
    if (threadIdx.x == 0) ctrl[b].total = base + cnt;
  } else if (cnt <= 4096u) {
    for (int k = threadIdx.x; k < (int)cnt; k += 256) si[k] = eqBuf[b * EQCAP + k];
    __syncthreads();
    for (int e = threadIdx.x; e < (int)cnt; e += 256) {
      const unsigned my = si[e];
      unsigned rank = 0;
      for (unsigned f = 0; f < cnt; ++f) rank += (si[f] < my) ? 1u : 0u;
      if (rank < need) sel[b * KPAD + base + rank] = thrHi | (unsigned long long)my;
    }
    if (threadIdx.x == 0) ctrl[b].total = base + need;
  } else {
    for (int k = threadIdx.x; k < EQCAP; k += 256)
      si[k] = (k < (int)cnt) ? eqBuf[b * EQCAP + k] : 0xFFFFFFFFu;
    __syncthreads();
    for (int k = 2; k <= EQCAP; k <<= 1)
      for (int j = k >> 1; j > 0; j >>= 1) {
        for (int idx = threadIdx.x; idx < EQCAP; idx += 256) {
          const int p = idx ^ j;
          if (p > idx) {
            const unsigned a = si[idx], c = si[p];
            const bool up = ((idx & k) == 0);
            if ((a > c) == up) { si[idx] = c; si[p] = a; }
          }
        }
        __syncthreads();
      }
    for (unsigned e = threadIdx.x; e < need; e += 256)
      sel[b * KPAD + base + e] = thrHi | (unsigned long long)si[e];
    if (threadIdx.x == 0) ctrl[b].total = base + need;
  }
}

// Pairwise rank + fused decode. key = (scorebits<<32) | ~idx; rank = #{keys > mine}.
// 1D grid, b = blockIdx.x & 7 (XCD affinity: image b's boxes written from XCD b).
__global__ __launch_bounds__(256) void rank_kernel(const Ctrl* __restrict__ ctrl,
                                                   const unsigned long long* __restrict__ sel,
                                                   const float* __restrict__ anchors,
                                                   const float* __restrict__ bbox,
                                                   float4* __restrict__ boxes, int N) {
  const int b = blockIdx.x & 7;
  const int it = blockIdx.x >> 3;    // 0..93
  const int tid = threadIdx.x;
  const int wv = tid >> 6, lane = tid & 63;
  __shared__ unsigned long long skey[KPAD];   // 48128 B
  __shared__ unsigned scnt[4][64];
  int total = (int)ctrl[b].total; if (total > KSEL) total = KSEL;
  for (int i = tid; i < KPAD; i += 256) {
    unsigned long long kp = 0ull;
    if (i < total) {
      const unsigned long long e = sel[b * KPAD + i];
      kp = (e & 0xFFFFFFFF00000000ull) | (unsigned long long)(0xFFFFFFFFu - (unsigned)e);
    }
    skey[i] = kp;
  }
  __syncthreads();
  const int me = it * 64 + lane;
  const unsigned long long myk = skey[me];
  const int chunk = KPAD / 4;
  const int lo = wv * chunk;
  unsigned cnt = 0;
#pragma unroll 8
  for (int c = 0; c < chunk; ++c) cnt += (skey[lo + c] > myk) ? 1u : 0u;
  scnt[wv][lane] = cnt;
  __syncthreads();
  if (wv == 0 && me < total) {
    const unsigned rank = scnt[0][lane] + scnt[1][lane] + scnt[2][lane] + scnt[3][lane];
    unsigned idx = 0xFFFFFFFFu - (unsigned)myk;
    if (idx >= (unsigned)N) idx = 0;
    const float4 A = ((const float4*)anchors)[(size_t)b * N + idx];
    const float4 R = ((const float4*)bbox)[(size_t)b * N + idx];
    const float d0 = R.x * 0.1f, d1 = R.y * 0.1f, d2 = R.z * 0.2f, d3 = R.w * 0.2f;
    const float h = A.z - A.x;
    const float w = A.w - A.y;
    const float cy = A.x + 0.5f * h + d0 * h;
    const float cx = A.y + 0.5f * w + d1 * w;
    const float e2 = (float)exp((double)d2);  // correctly-rounded f32 exp
    const float e3 = (float)exp((double)d3);
    const float h2 = h * e2;
    const float w2 = w * e3;
    float y1 = cy - 0.5f * h2;
    float x1 = cx - 0.5f * w2;
    float y2 = y1 + h2;
    float x2 = x1 + w2;
    y1 = fminf(fmaxf(y1, 0.0f), 1.0f);
    x1 = fminf(fmaxf(x1, 0.0f), 1.0f);
    y2 = fminf(fmaxf(y2, 0.0f), 1.0f);
    x2 = fminf(fmaxf(x2, 0.0f), 1.0f);
    boxes[b * KPAD + rank] = make_float4(y1, x1, y2, x2);
  }
}

// ---- 2048x2048 upper-triangular suppression matrix, COLUMN-word-major ----
// mat[((b*SWORDS)+w)*RMAX + i] = columns [w*64,w*64+64) of row i; written for w >= i>>6.
// Diagonal word zeroes bits c <= i. Sub-diagonal words are uninitialized — never loaded
// (scan gates lane >= chunk) and provably never tested. 1D grid, b = blockIdx.x & 7.
__global__ __launch_bounds__(256) void suppmat_kernel(const float4* __restrict__ boxes,
                                                      unsigned long long* __restrict__ mat) {
  const int b = blockIdx.x & 7;
  const int it = blockIdx.x >> 3;       // row tile 0..RTILES-1
  const int wv = threadIdx.x >> 6;
  const int lane = threadIdx.x & 63;
  const float4* gbox = boxes + b * KPAD;
  __shared__ float4 srow[64];
  __shared__ float sarea[64];
  __shared__ unsigned long long wbuf[64][SWORDS];   // 16 KiB
  if (threadIdx.x < 64) {
    const float4 v = gbox[it * 64 + threadIdx.x];
    srow[threadIdx.x] = v;
    sarea[threadIdx.x] = (v.z - v.x) * (v.w - v.y);
  }
  __syncthreads();
  float4 rb[16]; float rba[16];
#pragma unroll
  for (int k = 0; k < 16; ++k) { rb[k] = srow[wv * 16 + k]; rba[k] = sarea[wv * 16 + k]; }
  const double M = 0.7000000178813934326171875;
  for (int jt = it; jt < SWORDS; ++jt) {
    const int c = jt * 64 + lane;
    const float4 cv = gbox[c];
    const float ca = (cv.z - cv.x) * (cv.w - cv.y);
#pragma unroll
    for (int k = 0; k < 16; ++k) {
      const int i = it * 64 + wv * 16 + k;
      const float4 hb = rb[k];
      const float ha = rba[k];
      const float iy1 = fmaxf(hb.x, cv.x);
      const float ix1 = fmaxf(hb.y, cv.y);
      const float iy2 = fminf(hb.z, cv.z);
      const float ix2 = fminf(hb.w, cv.w);
      const float dy = fmaxf(iy2 - iy1, 0.0f);
      const float dx = fmaxf(ix2 - ix1, 0.0f);
      const float inter = dy * dx;
      const float denom = ha + ca - inter + 1e-12f;
      const bool s = (c > i) && ((double)inter >= M * (double)denom);
      const unsigned long long w = __ballot(s);
      if (lane == 0) wbuf[wv * 16 + k][jt] = w;
    }
  }
  __syncthreads();
  const int nw = SWORDS - it;
  unsigned long long* obase = mat + (size_t)(b * SWORDS) * RMAX;
  for (int q = threadIdx.x; q < 64 * nw; q += 256) {
    const int r = q & 63;        // row within tile -> coalesced over r
    const int k = q >> 6;        // word offset
    obase[(size_t)(it + k) * RMAX + it * 64 + r] = wbuf[r][it + k];
  }
}

// Chunked serial-scan exact greedy NMS. One wave per image; 64 rows resolved per chunk.
// Lane l (<SWORDS) owns removed-word l. Per chunk: 1 coalesced diag-word load, 1 shfl for
// the alive mask, branchless 64-step replay (shfl-broadcast colmasks), then per-lane OR of
// accepted rows' words (independent loads, lane >= chunk only — sub-diagonal never touched).
// Fallback (RMAX rows exhausted with nsel < PROP): direct-IoU continuation — exact.
__global__ __launch_bounds__(64) void nmsscan_kernel(const Ctrl* __restrict__ ctrl,
                                                     const float4* __restrict__ boxes,
                                                     const unsigned long long* __restrict__ mat,
                                                     float* __restrict__ out) {
  const int b = blockIdx.x;
  const int lane = threadIdx.x;
  int total = (int)ctrl[b].total; if (total > KSEL) total = KSEL;
  const unsigned long long* cmat = mat + (size_t)(b * SWORDS) * RMAX;  // [w][row]
  const float4* gbox = boxes + b * KPAD;
  float4* outv = (float4*)(out + (size_t)b * PROP * 4);
  __shared__ int s_sel[PROP];
  __shared__ float4 s_hbox[PROP];
  const int lim = (total < RMAX) ? total : RMAX;
  const int nchunks = (lim + 63) >> 6;
  const bool wlane = lane < SWORDS;
  unsigned long long r0 = 0ull;     // removed word `lane`
  int nsel = 0;

  unsigned long long diagN = (lane < lim) ? cmat[lane] : 0ull;  // chunk 0 diag (w=0, rows 0..63)
  for (int c = 0; c < nchunks; ++c) {
    const int base = c << 6;
    const int n = ((lim - base) < 64) ? (lim - base) : 64;
    const unsigned long long diag = diagN;
    // prefetch next chunk's diagonal word (independent of the chain)
    const int nb2 = base + 64;
    diagN = ((c + 1) < nchunks && (nb2 + lane) < lim)
              ? cmat[(size_t)(c + 1) * RMAX + nb2 + lane] : 0ull;
    // alive mask for this chunk
    unsigned long long aw = ~__shfl(r0, c, 64);
    if (n < 64) aw &= ((1ull << n) - 1ull);
    // branchless greedy replay; colmask_i broadcast from lane i (independent shfls)
    unsigned long long acc = 0ull;
#pragma unroll
    for (int i = 0; i < 64; ++i) {
      const unsigned long long cm = __shfl(diag, i, 64);
      const unsigned long long take = 0ull - ((aw >> i) & 1ull);
      acc |= (1ull << i) & take;
      aw &= ~(cm & take);
    }
    // budget truncation: keep earliest
    const int need = PROP - nsel;
    int na = __popcll(acc);
    if (na > need) {
      unsigned long long t2 = acc, a2 = 0ull;
      for (int c2 = 0; c2 < need; ++c2) { a2 |= t2 & (0ull - t2); t2 &= t2 - 1ull; }
      acc = a2; na = need;
    }
    if ((acc >> lane) & 1ull) {
      const int r = __popcll(acc & ((1ull << lane) - 1ull));
      s_sel[nsel + r] = base + lane;
    }
    nsel += na;
    if (nsel >= PROP || c + 1 >= nchunks) { if (nsel >= PROP) break; else continue; }
    // removed-set update: OR accepted rows' words (valid words only: lane >= c)
    if (wlane && lane >= c) {
      unsigned long long t2 = acc;
      unsigned long long o = r0;
      const unsigned long long* colw = cmat + (size_t)lane * RMAX + base;
      while (t2) {
        const int r = __builtin_ctzll(t2);
        t2 &= t2 - 1ull;
        o |= colw[r];
      }
      r0 = o;
    }
  }
  // fallback: rows >= RMAX via direct IoU (exact same criterion); not taken for light suppression
  if (nsel < PROP && total > lim) {
    for (int k = lane; k < nsel; k += 64) s_hbox[k] = gbox[s_sel[k]];
    __syncthreads();
    const double M = 0.7000000178813934326171875;
    for (int i2 = lim; i2 < total && nsel < PROP; ++i2) {
      const float4 v = gbox[i2];
      const float a = (v.z - v.x) * (v.w - v.y);
      bool supp = false;
      for (int h = lane; h < nsel; h += 64) {
        const float4 hb = s_hbox[h];
        const float ha = (hb.z - hb.x) * (hb.w - hb.y);
        const float iy1 = fmaxf(hb.x, v.x);
        const float ix1 = fmaxf(hb.y, v.y);
        const float iy2 = fminf(hb.z, v.z);
        const float ix2 = fminf(hb.w, v.w);
        const float dy = fmaxf(iy2 - iy1, 0.0f);
        const float dx = fmaxf(ix2 - ix1, 0.0f);
        const float inter = dy * dx;
        const float denom = ha + a - inter + 1e-12f;
        if ((double)inter >= M * (double)denom) { supp = true; break; }
      }
      if (!__any(supp)) {
        if (lane == 0) { s_sel[nsel] = i2; s_hbox[nsel] = v; }
        ++nsel;
      }
    }
  }
  __syncthreads();
  for (int k = lane; k < PROP; k += 64)
    outv[k] = (k < nsel) ? gbox[s_sel[k]] : make_float4(0.f, 0.f, 0.f, 0.f);
}

// ---- fallback windowed NMS (boxes-only) for small ws ----
__global__ __launch_bounds__(1024) void nms_kernel(const float4* __restrict__ boxes, float* __restrict__ out) {
  const int b = blockIdx.x;
  const int tid = threadIdx.x;
  const int lane = tid & 63;
  const float4* gbox = boxes + b * KPAD;
  float* outB = out + b * (PROP * 4);
  __shared__ unsigned long long smask[94];
  __shared__ int s_widx[64];
  __shared__ float4 s_wbox[64];
  __shared__ float s_wha[64];
  __shared__ int s_cnt, s_nAcc, s_total, s_cursor;
  for (int k = tid; k < 94; k += 1024)
    smask[k] = (k == 93) ? ((1ull << 48) - 1ull) : ~0ull;
  if (tid == 0) { s_cursor = 0; s_total = 0; }
  __syncthreads();
  const double M = 0.7000000178813934326171875;
  for (int round = 0; round < PROP; ++round) {
    if (tid == 0) {
      int cnt = 0;
      const int cur = s_cursor;
      int w = cur >> 6;
      unsigned long long word = (w < 94) ? (smask[w] & (~0ull << (cur & 63))) : 0ull;
      while (cnt < 64) {
        while (word == 0ull && ++w < 94) word = smask[w];
        if (w >= 94) break;
        const int bit = __builtin_ctzll(word);
        word &= word - 1ull;
        s_widx[cnt++] = (w << 6) | bit;
      }
      s_cnt = cnt;
      s_cursor = cnt ? (s_widx[cnt - 1] + 1) : KSEL;
    }
    __syncthreads();
    const int cnt = s_cnt;
    const int tailStart = s_cursor;
    if (cnt == 0) break;
    if (tid < 64) {
      const int j = (lane < cnt) ? s_widx[lane] : -1;
      float4 v = make_float4(0.f, 0.f, 0.f, 0.f);
      if (j >= 0) v = gbox[j];
      const float a = (v.z - v.x) * (v.w - v.y);
      const int totalOld = s_total;
      unsigned long long aliveW = __ballot(j >= 0);
      unsigned long long acc = 0ull;
      for (int i = 0; i < 64; ++i) {
        const float hx = __shfl(v.x, i), hy = __shfl(v.y, i);
        const float hz = __shfl(v.z, i), hw = __shfl(v.w, i);
        const float ha = __shfl(a, i);
        bool s = false;
        if (j >= 0 && lane > i) {
          const float iy1 = fmaxf(hx, v.x);
          const float ix1 = fmaxf(hy, v.y);
          const float iy2 = fminf(hz, v.z);
          const float ix2 = fminf(hw, v.w);
          const float dy = fmaxf(iy2 - iy1, 0.0f);
          const float dx = fmaxf(ix2 - ix1, 0.0f);
          const float inter = dy * dx;
          const float denom = ha + a - inter + 1e-12f;
          s = ((double)inter >= M * (double)denom);
        }
        const unsigned long long m = __ballot(s);
        if (aliveW & (1ull << i)) { acc |= 1ull << i; aliveW &= ~m; }
      }
      const int need = PROP - totalOld;
      int na = __popcll(acc);
      if (na > need) {
        unsigned long long t = acc, a2 = 0ull;
        for (int c2 = 0; c2 < need; ++c2) { a2 |= t & (0ull - t); t &= t - 1ull; }
        acc = a2; na = need;
      }
      if ((acc >> lane) & 1ull) {
        const int r = __popcll(acc & ((1ull << lane) - 1ull));
        float* o = outB + (size_t)(totalOld + r) * 4;
        o[0] = v.x; o[1] = v.y; o[2] = v.z; o[3] = v.w;
        s_wbox[r] = v; s_wha[r] = a;
      }
      if (lane == 0) { s_nAcc = na; s_total = totalOld + na; }
      if (j >= 0) atomicAnd(&smask[j >> 6], ~(1ull << (j & 63)));
    }
    __syncthreads();
    const int total = s_total;
    const int nAcc = s_nAcc;
    if (total >= PROP) break;
    for (int j = tailStart + tid; j < KSEL; j += 1024) {
      if (!((smask[j >> 6] >> (j & 63)) & 1ull)) continue;
      const float4 v = gbox[j];
      const float a = (v.z - v.x) * (v.w - v.y);
      bool supp = false;
      for (int r = 0; r < nAcc; ++r) {
        const float4 hb = s_wbox[r];
        const float ha = s_wha[r];
        const float iy1 = fmaxf(hb.x, v.x);
        const float ix1 = fmaxf(hb.y, v.y);
        const float iy2 = fminf(hb.z, v.z);
        const float ix2 = fminf(hb.w, v.w);
        const float dy = fmaxf(iy2 - iy1, 0.0f);
        const float dx = fmaxf(ix2 - ix1, 0.0f);
        const float inter = dy * dx;
        const float denom = ha + a - inter + 1e-12f;
        if ((double)inter >= M * (double)denom) { supp = true; break; }
      }
      if (supp) atomicAnd(&smask[j >> 6], ~(1ull << (j & 63)));
    }
    __syncthreads();
  }
  const int written = s_total;
  for (int u = written * 4 + tid; u < PROP * 4; u += 1024) outB[u] = 0.0f;
}

extern "C" void kernel_launch(void* const* d_in, const int* in_sizes, int n_in,
                              void* d_out, int out_size, void* d_ws, size_t ws_size,
                              hipStream_t stream) {
  (void)n_in; (void)out_size;
  const float* probs = (const float*)d_in[0];
  const float* bbox = (const float*)d_in[1];
  const float* anchors = (const float*)d_in[2];
  float* out = (float*)d_out;
  char* ws = (char*)d_ws;
  const int N = in_sizes[0] / (NB * 2);  // 261888

  unsigned* hist1 = (unsigned*)(ws + OFF_HIST1);
  unsigned* hist2 = (unsigned*)(ws + OFF_HIST2);
  unsigned* hist3 = (unsigned*)(ws + OFF_HIST3);
  Ctrl* ctrl = (Ctrl*)(ws + OFF_CTRL);
  unsigned long long* sel = (unsigned long long*)(ws + OFF_SEL);
  unsigned* eqBuf = (unsigned*)(ws + OFF_EQ);
  float4* boxes = (float4*)(ws + OFF_BOX);
  unsigned long long* mat = (unsigned long long*)(ws + OFF_MAT);

  const int zeroN = (int)(OFF_SEL / 4);  // hist1+hist2+hist3+ctrl
  zero_kernel<<<dim3((zeroN + 255) / 256), dim3(256), 0, stream>>>((unsigned*)ws, zeroN);

  const int gx = (N + 4095) / 4096;      // 64
  hist_kernel<<<dim3(gx, NB), dim3(256), 0, stream>>>(1, probs, hist1, ctrl, N);
  scan_kernel<<<dim3(NB), dim3(64), 0, stream>>>(1, hist1, ctrl);
  hist_kernel<<<dim3(gx, NB), dim3(256), 0, stream>>>(2, probs, hist2, ctrl, N);
  scan_kernel<<<dim3(NB), dim3(64), 0, stream>>>(2, hist2, ctrl);
  hist_kernel<<<dim3(gx, NB), dim3(256), 0, stream>>>(3, probs, hist3, ctrl, N);
  scan_kernel<<<dim3(NB), dim3(64), 0, stream>>>(3, hist3, ctrl);
  compact_kernel<<<dim3(gx, NB), dim3(256), 0, stream>>>(probs, ctrl, sel, eqBuf, N);
  eqres_kernel<<<dim3(NB), dim3(256), 0, stream>>>(ctrl, eqBuf, sel);
  rank_kernel<<<dim3(NTILE * NB), dim3(256), 0, stream>>>(ctrl, sel, anchors, bbox, boxes, N);

  if (ws_size >= (size_t)OFF_MAT + MAT_BYTES) {
    suppmat_kernel<<<dim3(RTILES * NB), dim3(256), 0, stream>>>(boxes, mat);
    nmsscan_kernel<<<dim3(NB), dim3(64), 0, stream>>>(ctrl, boxes, mat, out);
  } else {
    nms_kernel<<<dim3(NB), dim3(1024), 0, stream>>>(boxes, out);
  }
}

// Round 11
// 232.518 us; speedup vs baseline: 1.4953x; 1.4953x over previous
//
#include <hip/hip_runtime.h>

#pragma clang fp contract(off)

#define NB 8
#define KSEL 6000
#define KPAD 6016
#define PROP 1000
#define EQCAP 8192
#define NTILE 94
#define RMAX 2048
#define RTILES 32
#define SWORDS 32

// ws layout (bytes)
#define OFF_HIST1 0u          // 8*4096*4 = 131072
#define OFF_HIST2 131072u     // 8*4096*4
#define OFF_HIST3 262144u     // 8*256*4 = 8192
#define OFF_CTRL  270336u     // 8*64 = 512
#define OFF_SEL   270848u     // 8*6016*8 = 385024
#define OFF_EQ    655872u     // 8*8192*4 = 262144
#define OFF_BOX   1110528u    // 8*6016*16 = 770048 -> end 1880576
#define OFF_MAT   1884160u    // 8*2048*32*8 = 4194304 -> end 6078464
#define MAT_BYTES 4194304ull

struct Ctrl {
  unsigned t1, rem1, t2, rem2, thr, needEq, selCount, eqCount, total;
  unsigned pad[7];
};

__global__ __launch_bounds__(256) void zero_kernel(unsigned* p, int n) {
  int i = blockIdx.x * 256 + threadIdx.x;
  if (i < n) p[i] = 0u;
}

// phase 1: bin = bits>>20 (4096 bins); phase 2: mid 12 bits within t1; phase 3: low 8 bits within (t1,t2)
__global__ __launch_bounds__(256) void hist_kernel(int phase, const float* __restrict__ probs,
                                                   unsigned* __restrict__ hist,
                                                   const Ctrl* __restrict__ ctrl, int N) {
  __shared__ unsigned lh[4096];
  const int b = blockIdx.y;
  const int nb = (phase == 3) ? 256 : 4096;
  for (int k = threadIdx.x; k < nb; k += 256) lh[k] = 0u;
  unsigned t1 = 0, pre24 = 0;
  if (phase == 2) t1 = ctrl[b].t1;
  if (phase == 3) pre24 = (ctrl[b].t1 << 12) | ctrl[b].t2;
  __syncthreads();
  const int start = blockIdx.x * 4096;
  const int end = min(start + 4096, N);
  for (int i = start + (int)threadIdx.x * 2; i < end; i += 512) {
    const float4 p2 = *(const float4*)(probs + ((size_t)b * N + i) * 2);
    const unsigned bits0 = __float_as_uint(p2.y);
    if (phase == 1) atomicAdd(&lh[bits0 >> 20], 1u);
    else if (phase == 2) { if ((bits0 >> 20) == t1) atomicAdd(&lh[(bits0 >> 8) & 0xFFFu], 1u); }
    else { if ((bits0 >> 8) == pre24) atomicAdd(&lh[bits0 & 0xFFu], 1u); }
    if (i + 1 < end) {
      const unsigned bits1 = __float_as_uint(p2.w);
      if (phase == 1) atomicAdd(&lh[bits1 >> 20], 1u);
      else if (phase == 2) { if ((bits1 >> 20) == t1) atomicAdd(&lh[(bits1 >> 8) & 0xFFFu], 1u); }
      else { if ((bits1 >> 8) == pre24) atomicAdd(&lh[bits1 & 0xFFu], 1u); }
    }
  }
  __syncthreads();
  for (int k = threadIdx.x; k < nb; k += 256) {
    const unsigned v = lh[k];
    if (v) atomicAdd(&hist[b * nb + k], v);
  }
}

// one wave per image: descending cumulative scan, find threshold bin
__global__ __launch_bounds__(64) void scan_kernel(int phase, const unsigned* __restrict__ hist,
                                                  Ctrl* __restrict__ ctrl) {
  const int b = blockIdx.x;
  const int lane = threadIdx.x;
  const int nb = (phase == 3) ? 256 : 4096;
  const int chunks = nb >> 6;
  const unsigned target = (phase == 1) ? 6000u : ((phase == 2) ? ctrl[b].rem1 : ctrl[b].rem2);
  const unsigned* h = hist + b * nb;
  const int topbin = nb - 1 - lane * chunks;
  unsigned mysum = 0;
  for (int c = 0; c < chunks; c++) mysum += h[topbin - c];
  unsigned cum = mysum;
  for (int off = 1; off < 64; off <<= 1) {
    const unsigned v = __shfl_up(cum, off, 64);
    if (lane >= off) cum += v;
  }
  const unsigned prev = cum - mysum;
  if (prev < target && cum >= target) {
    unsigned c2 = prev;
    for (int c = 0; c < chunks; c++) {
      const int bin = topbin - c;
      const unsigned hv = h[bin];
      if (c2 + hv >= target) {
        const unsigned rem = target - c2;
        if (phase == 1) { ctrl[b].t1 = (unsigned)bin; ctrl[b].rem1 = rem; }
        else if (phase == 2) { ctrl[b].t2 = (unsigned)bin; ctrl[b].rem2 = rem; }
        else {
          ctrl[b].thr = (ctrl[b].t1 << 20) | (ctrl[b].t2 << 8) | (unsigned)bin;
          ctrl[b].needEq = rem;
        }
        break;
      }
      c2 += hv;
    }
  }
}

__global__ __launch_bounds__(256) void compact_kernel(const float* __restrict__ probs, Ctrl* __restrict__ ctrl,
                                                      unsigned long long* __restrict__ sel,
                                                      unsigned* __restrict__ eqBuf, int N) {
  const int b = blockIdx.y;
  const unsigned THR = ctrl[b].thr;
  const int start = blockIdx.x * 4096;
  const int end = min(start + 4096, N);
  const int lane = threadIdx.x & 63;
  const int iters = (end - start + 255) / 256;
  for (int it = 0; it < iters; it++) {
    const int i = start + it * 256 + (int)threadIdx.x;
    const bool v = i < end;
    unsigned bits = 0u;
    if (v) bits = __float_as_uint(probs[(size_t)(b * N + i) * 2 + 1]);
    const bool gt = v && (bits > THR);
    const bool eq = v && (bits == THR);
    const unsigned long long mg = __ballot(gt);
    if (mg) {
      const int leader = __builtin_ctzll(mg);
      unsigned base = 0;
      if (lane == leader) base = atomicAdd(&ctrl[b].selCount, (unsigned)__builtin_popcountll(mg));
      base = (unsigned)__shfl((int)base, leader, 64);
      if (gt) {
        const int rank = __builtin_popcountll(mg & ((1ull << lane) - 1ull));
        const unsigned pos = base + (unsigned)rank;
        if (pos < (unsigned)KPAD) sel[b * KPAD + pos] = ((unsigned long long)bits << 32) | (unsigned)i;
      }
    }
    const unsigned long long me = __ballot(eq);
    if (me) {
      const int leader = __builtin_ctzll(me);
      unsigned base = 0;
      if (lane == leader) base = atomicAdd(&ctrl[b].eqCount, (unsigned)__builtin_popcountll(me));
      base = (unsigned)__shfl((int)base, leader, 64);
      if (eq) {
        const int rank = __builtin_popcountll(me & ((1ull << lane) - 1ull));
        const unsigned pos = base + (unsigned)rank;
        if (pos < (unsigned)EQCAP) eqBuf[b * EQCAP + pos] = (unsigned)i;
      }
    }
  }
}

// resolve ties at the exact threshold: take lowest indices
__global__ __launch_bounds__(256) void eqres_kernel(Ctrl* __restrict__ ctrl, const unsigned* __restrict__ eqBuf,
                                                    unsigned long long* __restrict__ sel) {
  __shared__ unsigned si[EQCAP];
  const int b = blockIdx.x;
  const unsigned need = ctrl[b].needEq;
  unsigned cnt = ctrl[b].eqCount; if (cnt > EQCAP) cnt = EQCAP;
  const unsigned base = ctrl[b].selCount;
  const unsigned long long thrHi = ((unsigned long long)ctrl[b].thr) << 32;
  if (cnt <= need) {
    for (unsigned e = threadIdx.x; e < cnt; e += 256)
      sel[b * KPAD + base + e] = thrHi | (unsigned long long)eqBuf[b * EQCAP + e];
    if (threadIdx.x == 0) ctrl[b].total = base + cnt;
  } else if (cnt <= 4096u) {
    for (int k = threadIdx.x; k < (int)cnt; k += 256) si[k] = eqBuf[b * EQCAP + k];
    __syncthreads();
    for (int e = threadIdx.x; e < (int)cnt; e += 256) {
      const unsigned my = si[e];
      unsigned rank = 0;
      for (unsigned f = 0; f < cnt; ++f) rank += (si[f] < my) ? 1u : 0u;
      if (rank < need) sel[b * KPAD + base + rank] = thrHi | (unsigned long long)my;
    }
    if (threadIdx.x == 0) ctrl[b].total = base + need;
  } else {
    for (int k = threadIdx.x; k < EQCAP; k += 256)
      si[k] = (k < (int)cnt) ? eqBuf[b * EQCAP + k] : 0xFFFFFFFFu;
    __syncthreads();
    for (int k = 2; k <= EQCAP; k <<= 1)
      for (int j = k >> 1; j > 0; j >>= 1) {
        for (int idx = threadIdx.x; idx < EQCAP; idx += 256) {
          const int p = idx ^ j;
          if (p > idx) {
            const unsigned a = si[idx], c = si[p];
            const bool up = ((idx & k) == 0);
            if ((a > c) == up) { si[idx] = c; si[p] = a; }
          }
        }
        __syncthreads();
      }
    for (unsigned e = threadIdx.x; e < need; e += 256)
      sel[b * KPAD + base + e] = thrHi | (unsigned long long)si[e];
    if (threadIdx.x == 0) ctrl[b].total = base + need;
  }
}

// Pairwise rank + fused decode. key = (scorebits<<32) | ~idx; rank = #{keys > mine}.
// 1D grid, b = blockIdx.x & 7 (XCD affinity: image b's boxes written from XCD b).
__global__ __launch_bounds__(256) void rank_kernel(const Ctrl* __restrict__ ctrl,
                                                   const unsigned long long* __restrict__ sel,
                                                   const float* __restrict__ anchors,
                                                   const float* __restrict__ bbox,
                                                   float4* __restrict__ boxes, int N) {
  const int b = blockIdx.x & 7;
  const int it = blockIdx.x >> 3;    // 0..93
  const int tid = threadIdx.x;
  const int wv = tid >> 6, lane = tid & 63;
  __shared__ unsigned long long skey[KPAD];   // 48128 B
  __shared__ unsigned scnt[4][64];
  int total = (int)ctrl[b].total; if (total > KSEL) total = KSEL;
  for (int i = tid; i < KPAD; i += 256) {
    unsigned long long kp = 0ull;
    if (i < total) {
      const unsigned long long e = sel[b * KPAD + i];
      kp = (e & 0xFFFFFFFF00000000ull) | (unsigned long long)(0xFFFFFFFFu - (unsigned)e);
    }
    skey[i] = kp;
  }
  __syncthreads();
  const int me = it * 64 + lane;
  const unsigned long long myk = skey[me];
  const int chunk = KPAD / 4;
  const int lo = wv * chunk;
  unsigned cnt = 0;
#pragma unroll 8
  for (int c = 0; c < chunk; ++c) cnt += (skey[lo + c] > myk) ? 1u : 0u;
  scnt[wv][lane] = cnt;
  __syncthreads();
  if (wv == 0 && me < total) {
    const unsigned rank = scnt[0][lane] + scnt[1][lane] + scnt[2][lane] + scnt[3][lane];
    unsigned idx = 0xFFFFFFFFu - (unsigned)myk;
    if (idx >= (unsigned)N) idx = 0;
    const float4 A = ((const float4*)anchors)[(size_t)b * N + idx];
    const float4 R = ((const float4*)bbox)[(size_t)b * N + idx];
    const float d0 = R.x * 0.1f, d1 = R.y * 0.1f, d2 = R.z * 0.2f, d3 = R.w * 0.2f;
    const float h = A.z - A.x;
    const float w = A.w - A.y;
    const float cy = A.x + 0.5f * h + d0 * h;
    const float cx = A.y + 0.5f * w + d1 * w;
    const float e2 = (float)exp((double)d2);  // correctly-rounded f32 exp
    const float e3 = (float)exp((double)d3);
    const float h2 = h * e2;
    const float w2 = w * e3;
    float y1 = cy - 0.5f * h2;
    float x1 = cx - 0.5f * w2;
    float y2 = y1 + h2;
    float x2 = x1 + w2;
    y1 = fminf(fmaxf(y1, 0.0f), 1.0f);
    x1 = fminf(fmaxf(x1, 0.0f), 1.0f);
    y2 = fminf(fmaxf(y2, 0.0f), 1.0f);
    x2 = fminf(fmaxf(x2, 0.0f), 1.0f);
    boxes[b * KPAD + rank] = make_float4(y1, x1, y2, x2);
  }
}

// ---- 2048x2048 upper-triangular suppression matrix, row-major ----
// mat[((b*RMAX)+i)*SWORDS + w] = columns [w*64,w*64+64) of row i; written for w >= i>>6.
// Diagonal word zeroes bits c <= i. Sub-diagonal words uninitialized — only ORed into
// already-dead removed-words (word w is tested solely at chunk w, before any row of a
// later tile is accepted). 1D grid, b = blockIdx.x & 7 (XCD affinity).
__global__ __launch_bounds__(256) void suppmat_kernel(const float4* __restrict__ boxes,
                                                      unsigned long long* __restrict__ mat) {
  const int b = blockIdx.x & 7;
  const int it = blockIdx.x >> 3;       // row tile 0..RTILES-1
  const int wv = threadIdx.x >> 6;
  const int lane = threadIdx.x & 63;
  const float4* gbox = boxes + b * KPAD;
  __shared__ float4 srow[64];
  __shared__ float sarea[64];
  __shared__ unsigned long long wbuf[64][SWORDS];   // 16 KiB
  if (threadIdx.x < 64) {
    const float4 v = gbox[it * 64 + threadIdx.x];
    srow[threadIdx.x] = v;
    sarea[threadIdx.x] = (v.z - v.x) * (v.w - v.y);
  }
  __syncthreads();
  float4 rb[16]; float rba[16];
#pragma unroll
  for (int k = 0; k < 16; ++k) { rb[k] = srow[wv * 16 + k]; rba[k] = sarea[wv * 16 + k]; }
  const double M = 0.7000000178813934326171875;
  for (int jt = it; jt < SWORDS; ++jt) {
    const int c = jt * 64 + lane;
    const float4 cv = gbox[c];
    const float ca = (cv.z - cv.x) * (cv.w - cv.y);
#pragma unroll
    for (int k = 0; k < 16; ++k) {
      const int i = it * 64 + wv * 16 + k;
      const float4 hb = rb[k];
      const float ha = rba[k];
      const float iy1 = fmaxf(hb.x, cv.x);
      const float ix1 = fmaxf(hb.y, cv.y);
      const float iy2 = fminf(hb.z, cv.z);
      const float ix2 = fminf(hb.w, cv.w);
      const float dy = fmaxf(iy2 - iy1, 0.0f);
      const float dx = fmaxf(ix2 - ix1, 0.0f);
      const float inter = dy * dx;
      const float denom = ha + ca - inter + 1e-12f;
      const bool s = (c > i) && ((double)inter >= M * (double)denom);
      const unsigned long long w = __ballot(s);
      if (lane == 0) wbuf[wv * 16 + k][jt] = w;
    }
  }
  __syncthreads();
  const int nw = SWORDS - it;
  unsigned long long* obase = mat + ((size_t)b * RMAX + (size_t)it * 64) * SWORDS;
  for (int q = threadIdx.x; q < 64 * nw; q += 256) {
    const int r = q / nw;
    const int k = q - r * nw;
    obase[(size_t)r * SWORDS + it + k] = wbuf[r][it + k];
  }
}

// Chunked exact greedy NMS with SPARSE replay. One wave per image; 64 rows per chunk.
// Strictly-upper colmasks => a row's alive bit is only cleared by EARLIER rows, so the
// final alive word after processing only rows with nonzero masks IS the accept mask.
// Chain length per chunk = popcount(ballot(diag!=0)) ~ 4-8, not 64. Removed-set update:
// 64 unrolled unconditional coalesced loads (row-major), select-masked by acc.
// Fallback (RMAX exhausted with nsel < PROP): direct-IoU continuation — exact.
__global__ __launch_bounds__(64) void nmsscan_kernel(const Ctrl* __restrict__ ctrl,
                                                     const float4* __restrict__ boxes,
                                                     const unsigned long long* __restrict__ mat,
                                                     float* __restrict__ out) {
  const int b = blockIdx.x;
  const int lane = threadIdx.x;
  int total = (int)ctrl[b].total; if (total > KSEL) total = KSEL;
  const unsigned long long* rmat = mat + (size_t)b * RMAX * SWORDS;  // [row][w]
  const float4* gbox = boxes + b * KPAD;
  float4* outv = (float4*)(out + (size_t)b * PROP * 4);
  __shared__ int s_sel[PROP];
  __shared__ float4 s_hbox[PROP];
  const int lim = (total < RMAX) ? total : RMAX;
  const int nchunks = (lim + 63) >> 6;
  const bool wlane = lane < SWORDS;
  unsigned long long r0 = 0ull;     // removed word `lane` (lanes 0..SWORDS-1)
  int nsel = 0;

  // prefetch chunk 0 diagonal word: mat[row=lane][w=0]
  unsigned long long diagN = (lane < lim) ? rmat[(size_t)lane * SWORDS] : 0ull;
  for (int c = 0; c < nchunks && nsel < PROP; ++c) {
    const int base = c << 6;
    const int n = ((lim - base) < 64) ? (lim - base) : 64;
    const unsigned long long diag = diagN;
    // prefetch next chunk's diagonal (independent of the serial chain)
    const int nb2 = base + 64;
    diagN = ((c + 1) < nchunks && (nb2 + lane) < lim)
              ? rmat[(size_t)(nb2 + lane) * SWORDS + (c + 1)] : 0ull;
    // alive word for this chunk (uniform across lanes)
    unsigned long long aw = ~__shfl(r0, c, 64);
    if (n < 64) aw &= ((1ull << n) - 1ull);
    // sparse chain: only rows with nonzero suppression masks can change aw
    unsigned long long S = __ballot(diag != 0ull);
    while (S) {
      const int s = __builtin_ctzll(S);
      S &= S - 1ull;
      const unsigned long long cm = __shfl(diag, s, 64);  // uniform loop: all lanes shfl
      if ((aw >> s) & 1ull) aw &= ~cm;                    // cm bits strictly > s
    }
    unsigned long long acc = aw;
    // budget truncation: keep earliest
    const int need = PROP - nsel;
    int na = __popcll(acc);
    if (na > need) {
      unsigned long long t2 = acc, a2 = 0ull;
      for (int c2 = 0; c2 < need; ++c2) { a2 |= t2 & (0ull - t2); t2 &= t2 - 1ull; }
      acc = a2; na = need;
    }
    if ((acc >> lane) & 1ull) {
      const int r = __popcll(acc & ((1ull << lane) - 1ull));
      s_sel[nsel + r] = base + lane;
    }
    nsel += na;
    if (nsel >= PROP || c + 1 >= nchunks) continue;  // loop condition exits
    // removed-set update: coalesced row-major loads (mat[base+r][lane]), select-masked.
    // Garbage sub-diagonal words (lane < c) land in already-tested removed words — dead.
    if (wlane) {
      const unsigned long long* rowbase = rmat + (size_t)base * SWORDS + lane;
      unsigned long long o = 0ull;
#pragma unroll
      for (int r = 0; r < 64; ++r) {
        const unsigned long long v = rowbase[(size_t)r * SWORDS];
        o |= (((acc >> r) & 1ull) ? v : 0ull);
      }
      r0 |= o;
    }
  }
  // fallback: rows >= RMAX via direct IoU (exact same criterion); not taken for light suppression
  if (nsel < PROP && total > lim) {
    for (int k = lane; k < nsel; k += 64) s_hbox[k] = gbox[s_sel[k]];
    __syncthreads();
    const double M = 0.7000000178813934326171875;
    for (int i2 = lim; i2 < total && nsel < PROP; ++i2) {
      const float4 v = gbox[i2];
      const float a = (v.z - v.x) * (v.w - v.y);
      bool supp = false;
      for (int h = lane; h < nsel; h += 64) {
        const float4 hb = s_hbox[h];
        const float ha = (hb.z - hb.x) * (hb.w - hb.y);
        const float iy1 = fmaxf(hb.x, v.x);
        const float ix1 = fmaxf(hb.y, v.y);
        const float iy2 = fminf(hb.z, v.z);
        const float ix2 = fminf(hb.w, v.w);
        const float dy = fmaxf(iy2 - iy1, 0.0f);
        const float dx = fmaxf(ix2 - ix1, 0.0f);
        const float inter = dy * dx;
        const float denom = ha + a - inter + 1e-12f;
        if ((double)inter >= M * (double)denom) { supp = true; break; }
      }
      if (!__any(supp)) {
        if (lane == 0) { s_sel[nsel] = i2; s_hbox[nsel] = v; }
        ++nsel;
      }
    }
  }
  __syncthreads();
  for (int k = lane; k < PROP; k += 64)
    outv[k] = (k < nsel) ? gbox[s_sel[k]] : make_float4(0.f, 0.f, 0.f, 0.f);
}

// ---- fallback windowed NMS (boxes-only) for small ws ----
__global__ __launch_bounds__(1024) void nms_kernel(const float4* __restrict__ boxes, float* __restrict__ out) {
  const int b = blockIdx.x;
  const int tid = threadIdx.x;
  const int lane = tid & 63;
  const float4* gbox = boxes + b * KPAD;
  float* outB = out + b * (PROP * 4);
  __shared__ unsigned long long smask[94];
  __shared__ int s_widx[64];
  __shared__ float4 s_wbox[64];
  __shared__ float s_wha[64];
  __shared__ int s_cnt, s_nAcc, s_total, s_cursor;
  for (int k = tid; k < 94; k += 1024)
    smask[k] = (k == 93) ? ((1ull << 48) - 1ull) : ~0ull;
  if (tid == 0) { s_cursor = 0; s_total = 0; }
  __syncthreads();
  const double M = 0.7000000178813934326171875;
  for (int round = 0; round < PROP; ++round) {
    if (tid == 0) {
      int cnt = 0;
      const int cur = s_cursor;
      int w = cur >> 6;
      unsigned long long word = (w < 94) ? (smask[w] & (~0ull << (cur & 63))) : 0ull;
      while (cnt < 64) {
        while (word == 0ull && ++w < 94) word = smask[w];
        if (w >= 94) break;
        const int bit = __builtin_ctzll(word);
        word &= word - 1ull;
        s_widx[cnt++] = (w << 6) | bit;
      }
      s_cnt = cnt;
      s_cursor = cnt ? (s_widx[cnt - 1] + 1) : KSEL;
    }
    __syncthreads();
    const int cnt = s_cnt;
    const int tailStart = s_cursor;
    if (cnt == 0) break;
    if (tid < 64) {
      const int j = (lane < cnt) ? s_widx[lane] : -1;
      float4 v = make_float4(0.f, 0.f, 0.f, 0.f);
      if (j >= 0) v = gbox[j];
      const float a = (v.z - v.x) * (v.w - v.y);
      const int totalOld = s_total;
      unsigned long long aliveW = __ballot(j >= 0);
      unsigned long long acc = 0ull;
      for (int i = 0; i < 64; ++i) {
        const float hx = __shfl(v.x, i), hy = __shfl(v.y, i);
        const float hz = __shfl(v.z, i), hw = __shfl(v.w, i);
        const float ha = __shfl(a, i);
        bool s = false;
        if (j >= 0 && lane > i) {
          const float iy1 = fmaxf(hx, v.x);
          const float ix1 = fmaxf(hy, v.y);
          const float iy2 = fminf(hz, v.z);
          const float ix2 = fminf(hw, v.w);
          const float dy = fmaxf(iy2 - iy1, 0.0f);
          const float dx = fmaxf(ix2 - ix1, 0.0f);
          const float inter = dy * dx;
          const float denom = ha + a - inter + 1e-12f;
          s = ((double)inter >= M * (double)denom);
        }
        const unsigned long long m = __ballot(s);
        if (aliveW & (1ull << i)) { acc |= 1ull << i; aliveW &= ~m; }
      }
      const int need = PROP - totalOld;
      int na = __popcll(acc);
      if (na > need) {
        unsigned long long t = acc, a2 = 0ull;
        for (int c2 = 0; c2 < need; ++c2) { a2 |= t & (0ull - t); t &= t - 1ull; }
        acc = a2; na = need;
      }
      if ((acc >> lane) & 1ull) {
        const int r = __popcll(acc & ((1ull << lane) - 1ull));
        float* o = outB + (size_t)(totalOld + r) * 4;
        o[0] = v.x; o[1] = v.y; o[2] = v.z; o[3] = v.w;
        s_wbox[r] = v; s_wha[r] = a;
      }
      if (lane == 0) { s_nAcc = na; s_total = totalOld + na; }
      if (j >= 0) atomicAnd(&smask[j >> 6], ~(1ull << (j & 63)));
    }
    __syncthreads();
    const int total = s_total;
    const int nAcc = s_nAcc;
    if (total >= PROP) break;
    for (int j = tailStart + tid; j < KSEL; j += 1024) {
      if (!((smask[j >> 6] >> (j & 63)) & 1ull)) continue;
      const float4 v = gbox[j];
      const float a = (v.z - v.x) * (v.w - v.y);
      bool supp = false;
      for (int r = 0; r < nAcc; ++r) {
        const float4 hb = s_wbox[r];
        const float ha = s_wha[r];
        const float iy1 = fmaxf(hb.x, v.x);
        const float ix1 = fmaxf(hb.y, v.y);
        const float iy2 = fminf(hb.z, v.z);
        const float ix2 = fminf(hb.w, v.w);
        const float dy = fmaxf(iy2 - iy1, 0.0f);
        const float dx = fmaxf(ix2 - ix1, 0.0f);
        const float inter = dy * dx;
        const float denom = ha + a - inter + 1e-12f;
        if ((double)inter >= M * (double)denom) { supp = true; break; }
      }
      if (supp) atomicAnd(&smask[j >> 6], ~(1ull << (j & 63)));
    }
    __syncthreads();
  }
  const int written = s_total;
  for (int u = written * 4 + tid; u < PROP * 4; u += 1024) outB[u] = 0.0f;
}

extern "C" void kernel_launch(void* const* d_in, const int* in_sizes, int n_in,
                              void* d_out, int out_size, void* d_ws, size_t ws_size,
                              hipStream_t stream) {
  (void)n_in; (void)out_size;
  const float* probs = (const float*)d_in[0];
  const float* bbox = (const float*)d_in[1];
  const float* anchors = (const float*)d_in[2];
  float* out = (float*)d_out;
  char* ws = (char*)d_ws;
  const int N = in_sizes[0] / (NB * 2);  // 261888

  unsigned* hist1 = (unsigned*)(ws + OFF_HIST1);
  unsigned* hist2 = (unsigned*)(ws + OFF_HIST2);
  unsigned* hist3 = (unsigned*)(ws + OFF_HIST3);
  Ctrl* ctrl = (Ctrl*)(ws + OFF_CTRL);
  unsigned long long* sel = (unsigned long long*)(ws + OFF_SEL);
  unsigned* eqBuf = (unsigned*)(ws + OFF_EQ);
  float4* boxes = (float4*)(ws + OFF_BOX);
  unsigned long long* mat = (unsigned long long*)(ws + OFF_MAT);

  const int zeroN = (int)(OFF_SEL / 4);  // hist1+hist2+hist3+ctrl
  zero_kernel<<<dim3((zeroN + 255) / 256), dim3(256), 0, stream>>>((unsigned*)ws, zeroN);

  const int gx = (N + 4095) / 4096;      // 64
  hist_kernel<<<dim3(gx, NB), dim3(256), 0, stream>>>(1, probs, hist1, ctrl, N);
  scan_kernel<<<dim3(NB), dim3(64), 0, stream>>>(1, hist1, ctrl);
  hist_kernel<<<dim3(gx, NB), dim3(256), 0, stream>>>(2, probs, hist2, ctrl, N);
  scan_kernel<<<dim3(NB), dim3(64), 0, stream>>>(2, hist2, ctrl);
  hist_kernel<<<dim3(gx, NB), dim3(256), 0, stream>>>(3, probs, hist3, ctrl, N);
  scan_kernel<<<dim3(NB), dim3(64), 0, stream>>>(3, hist3, ctrl);
  compact_kernel<<<dim3(gx, NB), dim3(256), 0, stream>>>(probs, ctrl, sel, eqBuf, N);
  eqres_kernel<<<dim3(NB), dim3(256), 0, stream>>>(ctrl, eqBuf, sel);
  rank_kernel<<<dim3(NTILE * NB), dim3(256), 0, stream>>>(ctrl, sel, anchors, bbox, boxes, N);

  if (ws_size >= (size_t)OFF_MAT + MAT_BYTES) {
    suppmat_kernel<<<dim3(RTILES * NB), dim3(256), 0, stream>>>(boxes, mat);
    nmsscan_kernel<<<dim3(NB), dim3(64), 0, stream>>>(ctrl, boxes, mat, out);
  } else {
    nms_kernel<<<dim3(NB), dim3(1024), 0, stream>>>(boxes, out);
  }
}